// Round 2
// baseline (180.080 us; speedup 1.0000x reference)
//
#include <hip/hip_runtime.h>
#include <math.h>

#define KE 14.3996f
#define R_MAX 6.0f

// ws layout (floats):
//  [0] ae  [1] 1/an  [2] pre = 0.5*KE*rs
//  [3..6]  coeffs (softplus)
//  [7..10] exps   (softplus)
//  [16..79] powtab[z] = z^ae  for z = 0..63
//  [128..]  R4 array: float4 per atom = {x, y, z, (float)Z}
#define WS_POW 16
#define WS_R4  128

__device__ __forceinline__ float softplus_f(float x) {
    return log1pf(expf(x));
}

__global__ void zbl_prep(const float* __restrict__ a_exp,
                         const float* __restrict__ a_num,
                         const float* __restrict__ coefficients,
                         const float* __restrict__ exponents,
                         const float* __restrict__ rep_scale,
                         float* __restrict__ ws,
                         float* __restrict__ out) {
    int t = threadIdx.x;  // launched with 64 threads, 1 block
    float ae = softplus_f(a_exp[0]);
    if (t == 0) {
        ws[0] = ae;
        ws[1] = 1.0f / softplus_f(a_num[0]);
        ws[2] = 0.5f * KE * softplus_f(rep_scale[0]);
        out[0] = 0.0f;   // d_out is poisoned 0xAA before every timed call
    }
    if (t < 4) {
        ws[3 + t] = softplus_f(coefficients[t]);
        ws[7 + t] = softplus_f(exponents[t]);
    }
    // pow table: Z in [1,50)
    ws[WS_POW + t] = (t > 0) ? expf(ae * logf((float)t)) : 0.0f;
}

__global__ __launch_bounds__(256) void r4_prep(const float* __restrict__ R,
                                               const int* __restrict__ Z,
                                               float4* __restrict__ R4,
                                               int n) {
    int i = blockIdx.x * blockDim.x + threadIdx.x;
    if (i < n) {
        float4 v;
        v.x = R[3 * i + 0];
        v.y = R[3 * i + 1];
        v.z = R[3 * i + 2];
        v.w = (float)Z[i];
        R4[i] = v;
    }
}

__device__ __forceinline__ float edge_term(float4 a, float4 b, bool self,
                                           const float* __restrict__ spow,
                                           float inv_an,
                                           float c0, float c1, float c2, float c3,
                                           float e0, float e1, float e2, float e3) {
    const float dx = b.x - a.x;
    const float dy = b.y - a.y;
    const float dz = b.z - a.z;
    const float dr2 = dx * dx + dy * dy + dz * dz;
    if (self || dr2 >= R_MAX * R_MAX) return 0.0f;
    const float dr = fmaxf(__fsqrt_rn(dr2), 0.02f);
    const int zi_i = (int)a.w;
    const int zj_i = (int)b.w;
    const float pa = spow[zi_i] + spow[zj_i];      // Z_i^ae + Z_j^ae
    const float dist = dr * pa * inv_an;
    const float f = c0 * __expf(-e0 * dist) + c1 * __expf(-e1 * dist)
                  + c2 * __expf(-e2 * dist) + c3 * __expf(-e3 * dist);
    const float cut = 0.5f * (__cosf((float)M_PI / R_MAX * dr) + 1.0f);
    return a.w * b.w / dr * f * cut;
}

__global__ __launch_bounds__(256) void zbl_edges(
        const float4* __restrict__ R4,
        const int*   __restrict__ idx_i,
        const int*   __restrict__ idx_j,
        const float* __restrict__ ws,
        float*       __restrict__ out,
        int nE) {
    __shared__ float spow[64];
    __shared__ float ssc[11];
    if (threadIdx.x < 64) spow[threadIdx.x] = ws[WS_POW + threadIdx.x];
    if (threadIdx.x < 11) ssc[threadIdx.x] = ws[threadIdx.x];
    __syncthreads();

    const float inv_an = ssc[1];
    const float c0 = ssc[3], c1 = ssc[4], c2 = ssc[5], c3 = ssc[6];
    const float e0 = ssc[7], e1 = ssc[8], e2 = ssc[9], e3 = ssc[10];

    float local = 0.0f;
    const int e = (blockIdx.x * blockDim.x + threadIdx.x) * 4;

    if (e + 3 < nE) {
        // 4 edges per thread: 2 coalesced int4 idx loads + 8 independent
        // float4 gathers all issued before any compute (MLP for latency hiding)
        const int4 ii = *(const int4*)(idx_i + e);
        const int4 jj = *(const int4*)(idx_j + e);
        const float4 a0 = R4[ii.x], b0 = R4[jj.x];
        const float4 a1 = R4[ii.y], b1 = R4[jj.y];
        const float4 a2 = R4[ii.z], b2 = R4[jj.z];
        const float4 a3 = R4[ii.w], b3 = R4[jj.w];
        local += edge_term(a0, b0, ii.x == jj.x, spow, inv_an, c0,c1,c2,c3, e0,e1,e2,e3);
        local += edge_term(a1, b1, ii.y == jj.y, spow, inv_an, c0,c1,c2,c3, e0,e1,e2,e3);
        local += edge_term(a2, b2, ii.z == jj.z, spow, inv_an, c0,c1,c2,c3, e0,e1,e2,e3);
        local += edge_term(a3, b3, ii.w == jj.w, spow, inv_an, c0,c1,c2,c3, e0,e1,e2,e3);
    } else if (e < nE) {
        for (int k = e; k < nE; ++k) {
            const int i = idx_i[k];
            const int j = idx_j[k];
            local += edge_term(R4[i], R4[j], i == j, spow, inv_an, c0,c1,c2,c3, e0,e1,e2,e3);
        }
    }

    // 64-lane wave reduction
    for (int off = 32; off > 0; off >>= 1)
        local += __shfl_down(local, off);

    __shared__ float wsum[4];
    const int lane = threadIdx.x & 63;
    const int wave = threadIdx.x >> 6;
    if (lane == 0) wsum[wave] = local;
    __syncthreads();
    if (threadIdx.x == 0) {
        const float s = (wsum[0] + wsum[1] + wsum[2] + wsum[3]) * ssc[2];
        atomicAdd(out, s);
    }
}

extern "C" void kernel_launch(void* const* d_in, const int* in_sizes, int n_in,
                              void* d_out, int out_size, void* d_ws, size_t ws_size,
                              hipStream_t stream) {
    const float* R     = (const float*)d_in[0];
    const int*   Z     = (const int*)d_in[1];
    const int*   idx   = (const int*)d_in[2];
    const float* a_exp = (const float*)d_in[3];
    const float* a_num = (const float*)d_in[4];
    const float* coef  = (const float*)d_in[5];
    const float* expo  = (const float*)d_in[6];
    const float* rs    = (const float*)d_in[7];

    float* out = (float*)d_out;
    float* ws  = (float*)d_ws;

    const int nA = in_sizes[0] / 3;
    const int nE = in_sizes[2] / 2;
    const int* idx_i = idx;
    const int* idx_j = idx + nE;

    float4* R4 = (float4*)(ws + WS_R4);

    zbl_prep<<<1, 64, 0, stream>>>(a_exp, a_num, coef, expo, rs, ws, out);
    r4_prep<<<(nA + 255) / 256, 256, 0, stream>>>(R, Z, R4, nA);

    const int block = 256;
    const int per_block = block * 4;
    const int grid = (nE + per_block - 1) / per_block;
    zbl_edges<<<grid, block, 0, stream>>>(R4, idx_i, idx_j, ws, out, nE);
}